// Round 15
// baseline (259.799 us; speedup 1.0000x reference)
//
#include <hip/hip_runtime.h>

// GLIFR RNN (B=64, T=200, IN=512, HID=1024, OUT=512), fp32 in/out, bf16 MFMA.
//
// DELAY=20 decouples the lateral matmul -> 10 chunks of 20 steps.
//
// Round 17: R15 base (243.3; persistent-flag chain permanently shelved after
// 2 correctness failures). Chain TLP via M-SPLIT: 32 b-groups of 2 b x 16
// h-tiles = 512 blocks = 2 blocks/CU. Unlike R6's N-split (doubled A-panel
// HBM/L3 traffic -> net loss), the M-split is traffic-neutral in A (same
// total rows staged) and only doubles L2-local Wlat reads. Co-resident
// blocks sit at independent barriers -> each vmcnt(0) drain (~300-400 ns,
// R8-R11) is hidden by the other block's compute. LDS 56 KB (BK=128 double
// buffer) to fit 2 blocks/CU; M=40 rows padded to 48 MFMA rows (rows 40-47
// discarded; C rows are independent so garbage cannot contaminate).
// Wave layout 1x4 N-split: each wave TM=3 x TN=1 (16-col slice).
//
// Workspace (~84 MB, R15 offsets):
//   synb  bf16 [T,B,H]  @ 0          (26214400 B)  x_proj (read-only after GEMM)
//   state fp32 4x[B*H]  @ 52428800   (1048576 B)   volt, asc0, asc1, firing
//   F     bf16 [T,B,H]  @ 53477376   (26214400 B)  firing history
//     xb  bf16 [12800,512] overlays F (dead before first F write)
//   WinT  bf16 [H,IN]   @ 79691776   (1048576 B)
//   WlatT bf16 [H,H]    @ 80740352   (2097152 B)
//   WoutB bf16 [OUT,H]  @ 82837504   (1048576 B)

typedef float f32x4 __attribute__((ext_vector_type(4)));
typedef __bf16 bf16x8 __attribute__((ext_vector_type(8)));
typedef unsigned short ushortx8 __attribute__((ext_vector_type(8)));
typedef unsigned short ushortx4 __attribute__((ext_vector_type(4)));

__device__ __forceinline__ unsigned short f2b(float f) {
    unsigned int u = __float_as_uint(f);
    unsigned int r = u + 0x7FFFu + ((u >> 16) & 1u);   // RNE
    return (unsigned short)(r >> 16);
}
__device__ __forceinline__ float b2f(unsigned short u) {
    return __uint_as_float(((unsigned int)u) << 16);
}
__device__ __forceinline__ float sigmoidf(float x) {
    return 1.0f / (1.0f + __expf(-x));
}

// async global->LDS, 16 B per lane; lptr must be wave-uniform (HW adds lane*16)
__device__ __forceinline__ void gl_lds16(const unsigned short* g, unsigned short* l) {
    __builtin_amdgcn_global_load_lds(
        (const __attribute__((address_space(1))) void*)g,
        (__attribute__((address_space(3))) void*)l, 16, 0, 0);
}

// ---------------------------------------------------------------------------
// prep_all: one dispatch for all weight/input preprocessing (role by blockIdx).
// ---------------------------------------------------------------------------
__global__ __launch_bounds__(256) void prep_all(
    const float* __restrict__ W_in, const float* __restrict__ W_lat,
    const float* __restrict__ W_out, const float* __restrict__ x,
    unsigned short* __restrict__ WinT, unsigned short* __restrict__ WlatT,
    unsigned short* __restrict__ WoutB, unsigned short* __restrict__ xb)
{
    __shared__ unsigned short t[64][65];
    const int blk = blockIdx.x, tid = threadIdx.x;

    if (blk < 128) {                       // Win transpose
        int bx = (blk & 15) * 64, by = (blk >> 4) * 64;
        int tx = tid & 63, ty = tid >> 6;
        for (int r = ty; r < 64; r += 4)
            t[r][tx] = f2b(W_in[(size_t)(by + r) * 1024 + bx + tx]);
        __syncthreads();
        for (int r = ty; r < 64; r += 4)
            WinT[(size_t)(bx + r) * 512 + by + tx] = t[tx][r];
    } else if (blk < 384) {                // Wlat transpose
        int b2 = blk - 128;
        int bx = (b2 & 15) * 64, by = (b2 >> 4) * 64;
        int tx = tid & 63, ty = tid >> 6;
        for (int r = ty; r < 64; r += 4)
            t[r][tx] = f2b(W_lat[(size_t)(by + r) * 1024 + bx + tx]);
        __syncthreads();
        for (int r = ty; r < 64; r += 4)
            WlatT[(size_t)(bx + r) * 1024 + by + tx] = t[tx][r];
    } else if (blk < 896) {                // Wout convert
        int i = ((blk - 384) * 256 + tid) * 4;
        f32x4 v = *(const f32x4*)(W_out + i);
        ushortx4 o;
        o[0] = f2b(v[0]); o[1] = f2b(v[1]); o[2] = f2b(v[2]); o[3] = f2b(v[3]);
        *(ushortx4*)(WoutB + i) = o;
    } else {                               // x convert
        size_t i8 = (size_t)((blk - 896) * 256 + tid) * 8;
        int m = (int)(i8 >> 9), k = (int)(i8 & 511);
        int b = m & 63, tt = m >> 6;
        const float* src = x + ((size_t)b * 200 + tt) * 512 + k;
        f32x4 v0 = *(const f32x4*)src;
        f32x4 v1 = *(const f32x4*)(src + 4);
        ushortx8 o;
        o[0] = f2b(v0[0]); o[1] = f2b(v0[1]); o[2] = f2b(v0[2]); o[3] = f2b(v0[3]);
        o[4] = f2b(v1[0]); o[5] = f2b(v1[1]); o[6] = f2b(v1[2]); o[7] = f2b(v1[3]);
        *(ushortx8*)(xb + i8) = o;
    }
}

// ---------------------------------------------------------------------------
// NT GEMM (R15: XCD-grouped swizzle; MODE 0 writes bf16, MODE 2 fp32+bias).
// ---------------------------------------------------------------------------
template<int BM, int BN, int MODE>
__global__ __launch_bounds__(256) void gemm_nt(
    const unsigned short* __restrict__ A,
    const unsigned short* __restrict__ Bt,
    float* __restrict__ outf,
    unsigned short* __restrict__ outb,
    const float* __restrict__ bias,
    int M, int N, int K, int t_base)
{
    constexpr int WM = BM / 2, WN = BN / 2;
    constexpr int TM = WM / 16, TN = WN / 16;

    __shared__ unsigned short Asm[BM * 64];
    __shared__ unsigned short Bsm[BN * 64];

    const int tid  = threadIdx.x;
    const int wave = tid >> 6, lane = tid & 63;
    const int m16  = lane & 15, quad = lane >> 4;
    const int nwg = gridDim.x * gridDim.y;
    const int d   = blockIdx.y * gridDim.x + blockIdx.x;
    const int l   = (d & 7) * (nwg >> 3) + (d >> 3);
    const int bm0 = (l / gridDim.x) * BM, bn0 = (l % gridDim.x) * BN;
    const int wr   = (wave >> 1) * WM, wc = (wave & 1) * WN;
    const int sr   = lane >> 3;
    const int sc   = lane & 7;

    f32x4 acc[TM][TN];
#pragma unroll
    for (int i = 0; i < TM; i++)
#pragma unroll
        for (int j = 0; j < TN; j++)
            acc[i][j] = (f32x4){0.f, 0.f, 0.f, 0.f};

    for (int k0 = 0; k0 < K; k0 += 64) {
#pragma unroll
        for (int g = wave; g < BM / 8; g += 4) {
            int r = g * 8 + sr;
            int c = sc ^ (r & 7);
            gl_lds16(A + (size_t)(bm0 + r) * K + k0 + c * 8, Asm + g * 512);
        }
#pragma unroll
        for (int g = wave; g < BN / 8; g += 4) {
            int r = g * 8 + sr;
            int c = sc ^ (r & 7);
            gl_lds16(Bt + (size_t)(bn0 + r) * K + k0 + c * 8, Bsm + g * 512);
        }
        __syncthreads();

        ushortx8 af[2][TM], bfr[2][TN];
#pragma unroll
        for (int kh = 0; kh < 2; kh++) {
#pragma unroll
            for (int i = 0; i < TM; i++) {
                int ra = wr + i * 16 + m16;
                af[kh][i] = *(const ushortx8*)(
                    Asm + ra * 64 + (((kh * 4 + quad) ^ (ra & 7)) * 8));
            }
#pragma unroll
            for (int j = 0; j < TN; j++) {
                int rb = wc + j * 16 + m16;
                bfr[kh][j] = *(const ushortx8*)(
                    Bsm + rb * 64 + (((kh * 4 + quad) ^ (rb & 7)) * 8));
            }
        }
#pragma unroll
        for (int i = 0; i < TM; i++)
#pragma unroll
            for (int j = 0; j < TN; j++) {
                acc[i][j] = __builtin_amdgcn_mfma_f32_16x16x32_bf16(
                    __builtin_bit_cast(bf16x8, af[0][i]),
                    __builtin_bit_cast(bf16x8, bfr[0][j]),
                    acc[i][j], 0, 0, 0);
                acc[i][j] = __builtin_amdgcn_mfma_f32_16x16x32_bf16(
                    __builtin_bit_cast(bf16x8, af[1][i]),
                    __builtin_bit_cast(bf16x8, bfr[1][j]),
                    acc[i][j], 0, 0, 0);
            }
        __syncthreads();
    }

    // epilogue; C/D layout: col = lane&15, row = quad*4 + reg  (m89-verified)
#pragma unroll
    for (int i = 0; i < TM; i++)
#pragma unroll
        for (int j = 0; j < TN; j++) {
            int col = bn0 + wc + j * 16 + m16;
            float bv = (MODE == 2) ? bias[col] : 0.f;
#pragma unroll
            for (int v = 0; v < 4; v++) {
                int row = bm0 + wr + i * 16 + quad * 4 + v;
                if (MODE == 2) {
                    size_t o = (size_t)((row & 63) * 200 + t_base + (row >> 6)) * N + col;
                    outf[o] = acc[i][j][v] + bv;
                } else {
                    outb[(size_t)row * N + col] = f2b(acc[i][j][v]);
                }
            }
        }
}

// ---------------------------------------------------------------------------
// Fused lateral GEMM + 20-step GLIFR recurrence for one chunk.
// M-split for TLP: block tile M = 40 rows (20 t x 2 b, row r <-> t=r>>1,
// b=b0+(r&1)) padded to 48 MFMA rows (40-47 discarded), N = 64 h.
// Grid (16 h-tiles, 32 b-groups) = 512 blocks = 2 blocks/CU; co-resident
// blocks hide each other's vmcnt(0) drains. LDS 56 KB: BK=128 double buffer
// (A 48x256B x2, B 64x256B x2), 8 sub-steps, STAGE(next) before COMPUTE(cur).
// LDS row = 256 B = 16 slots of 16 B; slot c of row r holds chunk c^(r&15)
// (R8-proven swizzle). Waves: 1x4 N-split, each wave TM=3 x TN=1 (wc=wave*16).
// XCD-grouped swizzle: XCD k owns b-groups 4k..4k+3 (A-panel L2 locality).
// first=1 (chunk 0): skip GEMM; recurrence straight from bf16 x_proj.
// Recurrence threads 0..127: b_local = tid>>6, h_local = tid&63.
// ---------------------------------------------------------------------------
__global__ __launch_bounds__(256) void fused_chunk(
    const unsigned short* __restrict__ Fprev, // [1280,1024] bf16, rows t*64+b
    const unsigned short* __restrict__ Wlat,  // [1024,1024] bf16 NT
    const unsigned short* __restrict__ xproj, // [1280,1024] bf16 (syn chunk c)
    float* __restrict__ state,                // 4 x [B*H]
    unsigned short* __restrict__ Fc,          // F chunk c out
    const float* __restrict__ thresh,
    const float* __restrict__ t_km,
    const float* __restrict__ t_ak,
    const float* __restrict__ amp,
    const float* __restrict__ t_ar,
    int first)
{
    const int BH = 64 * 1024;
    __shared__ __align__(16) char lds[57344];
    unsigned short* A0 = (unsigned short*)lds;             // 48*256 B = 12288
    unsigned short* A1 = (unsigned short*)(lds + 12288);   // 48*256 B
    unsigned short* B0 = (unsigned short*)(lds + 24576);   // 64*256 B = 16384
    unsigned short* B1 = (unsigned short*)(lds + 40960);   // 64*256 B
    float* synT = (float*)lds;                             // 40*66 f32 = 10560 B

    const int tid  = threadIdx.x;
    const int wave = tid >> 6, lane = tid & 63;
    const int m16  = lane & 15, quad = lane >> 4;
    const int sr4  = lane >> 4;        // row within a 4-row staging group
    const int sc16 = lane & 15;        // LDS 16B slot within the 256B row
    // XCD-grouped swizzle: XCD d%8 owns b-groups 4(d%8)..4(d%8)+3.
    const int d    = blockIdx.y * 16 + blockIdx.x;
    const int l    = (d & 7) * 64 + (d >> 3);
    const int bg   = l >> 4;                 // b-group 0..31
    const int h0   = (l & 15) * 64, b0 = bg * 2;
    const int wc   = wave * 16;              // wave's 16-col N slice

    if (first) {
        // ---- chunk 0: recurrence straight from x_proj, zero state ----
        if (tid < 128) {
            const int b_local = tid >> 6, h_local = tid & 63;
            const int h    = h0 + h_local;
            const int gidx = (b0 + b_local) * 1024 + h;
            float th  = thresh[h];
            float sm  = sigmoidf(t_km[h]);
            float rm  = 0.1f * sm;
            float om  = 1.0f - sm;
            float sa0 = sigmoidf(t_ak[h]);
            float sa1 = sigmoidf(t_ak[1024 + h]);
            float am0 = amp[h];
            float am1 = amp[1024 + h];
            float r0  = 1.0f - 2.0f * sigmoidf(t_ar[h]);
            float r1  = 1.0f - 2.0f * sigmoidf(t_ar[1024 + h]);
            float volt = 0.f, as0 = 0.f, as1 = 0.f, fir = 0.f;
#pragma unroll
            for (int s = 0; s < 20; s++) {
                float sv  = b2f(xproj[(size_t)(s * 64 + b0 + b_local) * 1024 + h]);
                float na0 = (am0 + r0 * as0) * fir * sa0 + (1.f - sa0) * as0;
                float na1 = (am1 + r1 * as1) * fir * sa1 + (1.f - sa1) * as1;
                volt = rm * (sv + na0 + na1) + om * volt;
                fir  = sigmoidf(volt - th);
                Fc[(size_t)s * BH + gidx] = f2b(fir);
                as0 = na0; as1 = na1;
            }
            state[gidx]          = volt;
            state[BH + gidx]     = as0;
            state[2 * BH + gidx] = as1;
            state[3 * BH + gidx] = fir;
        }
        return;
    }

    f32x4 acc[3];
    // acc init = x_proj tile (bf16); rows >= 40 are padding (zero)
#pragma unroll
    for (int i = 0; i < 3; i++) {
#pragma unroll
        for (int v = 0; v < 4; v++) {
            int row = i * 16 + quad * 4 + v;
            int col = h0 + wc + m16;
            acc[i][v] = (row < 40)
                ? b2f(xproj[(size_t)(((row >> 1) << 6) + b0 + (row & 1)) * 1024 + col])
                : 0.f;
        }
    }

    // stage one K=128 sub-tile; A: 10 wave-instrs (40 rows), B: 16 (64 rows)
    auto STAGE = [&](unsigned short* Ad, unsigned short* Bd, int k0) {
        for (int g = wave; g < 10; g += 4) {
            int r = g * 4 + sr4;                        // 0..39
            int c = sc16 ^ (r & 15);                    // global-side swizzle
            int m = ((r >> 1) << 6) + b0 + (r & 1);
            gl_lds16(Fprev + (size_t)m * 1024 + k0 + c * 8, Ad + g * 512);
        }
        for (int g = wave; g < 16; g += 4) {
            int r = g * 4 + sr4;                        // 0..63
            int c = sc16 ^ (r & 15);
            gl_lds16(Wlat + (size_t)(h0 + r) * 1024 + k0 + c * 8, Bd + g * 512);
        }
    };
    // consume one K=128 sub-tile (R8-proven fragment pattern; TN=1)
    auto COMPUTE = [&](const unsigned short* As, const unsigned short* Bs) {
        ushortx8 af[4][3], bfr[4];
#pragma unroll
        for (int kh = 0; kh < 4; kh++) {
            int s = kh * 4 + quad;                      // slot 0..15
#pragma unroll
            for (int i = 0; i < 3; i++) {
                int ra = i * 16 + m16;                  // rows 0..47 (40+ pad)
                af[kh][i] = *(const ushortx8*)(
                    As + ra * 128 + ((s ^ (ra & 15)) * 8));
            }
            int rb = wc + m16;
            bfr[kh] = *(const ushortx8*)(
                Bs + rb * 128 + ((s ^ (rb & 15)) * 8));
        }
#pragma unroll
        for (int i = 0; i < 3; i++)
#pragma unroll
            for (int kh = 0; kh < 4; kh++)
                acc[i] = __builtin_amdgcn_mfma_f32_16x16x32_bf16(
                    __builtin_bit_cast(bf16x8, af[kh][i]),
                    __builtin_bit_cast(bf16x8, bfr[kh]), acc[i], 0, 0, 0);
    };

    // 2-phase pipeline over 8 sub-steps, fully unrolled (named buffers):
    STAGE(A0, B0, 0);
    __syncthreads();                        // fill drain
    STAGE(A1, B1, 128);  COMPUTE(A0, B0);  __syncthreads();
    STAGE(A0, B0, 256);  COMPUTE(A1, B1);  __syncthreads();
    STAGE(A1, B1, 384);  COMPUTE(A0, B0);  __syncthreads();
    STAGE(A0, B0, 512);  COMPUTE(A1, B1);  __syncthreads();
    STAGE(A1, B1, 640);  COMPUTE(A0, B0);  __syncthreads();
    STAGE(A0, B0, 768);  COMPUTE(A1, B1);  __syncthreads();
    STAGE(A1, B1, 896);  COMPUTE(A0, B0);  __syncthreads();
                         COMPUTE(A1, B1);  __syncthreads();

    // spill syn tile (40 valid rows) to LDS; stride 66 words.
#pragma unroll
    for (int i = 0; i < 3; i++) {
#pragma unroll
        for (int v = 0; v < 4; v++) {
            int row = i * 16 + quad * 4 + v;
            if (row < 40)
                synT[row * 66 + wc + m16] = acc[i][v];
        }
    }
    __syncthreads();

    // 20-step recurrence: threads 0..127 -> (b_local = tid>>6, h_local = tid&63)
    if (tid < 128) {
        const int b_local = tid >> 6, h_local = tid & 63;
        const int h    = h0 + h_local;
        const int gidx = (b0 + b_local) * 1024 + h;
        float th  = thresh[h];
        float sm  = sigmoidf(t_km[h]);
        float rm  = 0.1f * sm;
        float om  = 1.0f - sm;
        float sa0 = sigmoidf(t_ak[h]);
        float sa1 = sigmoidf(t_ak[1024 + h]);
        float am0 = amp[h];
        float am1 = amp[1024 + h];
        float r0  = 1.0f - 2.0f * sigmoidf(t_ar[h]);
        float r1  = 1.0f - 2.0f * sigmoidf(t_ar[1024 + h]);

        float volt = state[gidx];
        float as0  = state[BH + gidx];
        float as1  = state[2 * BH + gidx];
        float fir  = state[3 * BH + gidx];

#pragma unroll
        for (int s = 0; s < 20; s++) {
            float sv  = synT[(s * 2 + b_local) * 66 + h_local];
            float na0 = (am0 + r0 * as0) * fir * sa0 + (1.f - sa0) * as0;
            float na1 = (am1 + r1 * as1) * fir * sa1 + (1.f - sa1) * as1;
            volt = rm * (sv + na0 + na1) + om * volt;
            fir  = sigmoidf(volt - th);
            Fc[(size_t)s * BH + gidx] = f2b(fir);
            as0 = na0; as1 = na1;
        }
        state[gidx]          = volt;
        state[BH + gidx]     = as0;
        state[2 * BH + gidx] = as1;
        state[3 * BH + gidx] = fir;
    }
}

// ---------------------------------------------------------------------------
extern "C" void kernel_launch(void* const* d_in, const int* in_sizes, int n_in,
                              void* d_out, int out_size, void* d_ws, size_t ws_size,
                              hipStream_t stream)
{
    const float* x      = (const float*)d_in[0];  // [64,200,512]
    const float* W_in   = (const float*)d_in[1];  // [512,1024]
    const float* W_lat  = (const float*)d_in[2];  // [1024,1024]
    const float* thresh = (const float*)d_in[3];  // [1,1024]
    const float* t_km   = (const float*)d_in[4];  // [1,1024]
    const float* t_ak   = (const float*)d_in[5];  // [2,1,1024]
    const float* amp    = (const float*)d_in[6];  // [2,1,1024]
    const float* t_ar   = (const float*)d_in[7];  // [2,1,1024]
    const float* W_out  = (const float*)d_in[8];  // [512,1024] (n,k) already!
    const float* b_out  = (const float*)d_in[9];  // [512]
    float* out = (float*)d_out;                   // [64,200,512]

    char* ws = (char*)d_ws;
    unsigned short* synb  = (unsigned short*)ws;            // [T,B,H] bf16 x_proj
    float*          state = (float*)(ws + 52428800);
    unsigned short* F     = (unsigned short*)(ws + 53477376);
    unsigned short* xb    = F;  // overlay: dead before first F write
    unsigned short* WinT  = (unsigned short*)(ws + 79691776);
    unsigned short* WlatT = (unsigned short*)(ws + 80740352);
    unsigned short* WoutB = (unsigned short*)(ws + 82837504);

    // Prep (one dispatch): transposes/converts to bf16 NT layout, x to m-order.
    prep_all<<<4096, 256, 0, stream>>>(W_in, W_lat, W_out, x,
                                       WinT, WlatT, WoutB, xb);

    // x_proj (= synb, read-only from here on): [12800,1024] = xb @ WinT^T
    gemm_nt<128, 128, 0><<<dim3(1024 / 128, 12800 / 128), 256, 0, stream>>>(
        xb, WinT, nullptr, synb, nullptr, 12800, 1024, 512, 0);

    const size_t CHUNK = 20 * 64 * 1024;  // elements per chunk of [T,B,H]
    // chunk 0 (first=1: no lateral term, zero state) then chunks 1..9
    fused_chunk<<<dim3(16, 32), 256, 0, stream>>>(
        F, WlatT, synb, state, F, thresh, t_km, t_ak, amp, t_ar, 1);
    for (int c = 1; c < 10; c++) {
        fused_chunk<<<dim3(16, 32), 256, 0, stream>>>(
            F + (size_t)(c - 1) * CHUNK, WlatT,
            synb + (size_t)c * CHUNK, state, F + (size_t)c * CHUNK,
            thresh, t_km, t_ak, amp, t_ar, 0);
    }

    // readout: out[b,t,:] = F[t,b,:] @ W_out^T + b_out  (W_out already [n,k])
    gemm_nt<128, 128, 2><<<dim3(512 / 128, 12800 / 128), 256, 0, stream>>>(
        F, WoutB, out, nullptr, b_out, 12800, 512, 1024, 0);
}

// Round 16
// 241.593 us; speedup vs baseline: 1.0754x; 1.0754x over previous
//
#include <hip/hip_runtime.h>

// GLIFR RNN (B=64, T=200, IN=512, HID=1024, OUT=512), fp32 in/out, bf16 MFMA.
//
// DELAY=20 decouples the lateral matmul -> 10 chunks of 20 steps.
//
// Round 18: RESTORE R15 (best correct, 243.3). R17's M-split chain (+16.5)
// confirmed — with R6 (N-split), R7 (co-resident readout), R14/R16 (flag
// persistence, correctness failures) — that the chain's 1-block/CU, BK=256,
// double-buffered configuration is the local optimum; co-residency plays
// lose to added traffic / added barriers / coherence hazards.
// Structure: prep_all (1 dispatch) -> inGEMM (bf16 out) -> 10x fused_chunk
// (chunk0 folded via first=1) -> readout GEMM. XCD-grouped swizzles
// throughout. Session ledger: 316.5 -> 243.3.
//
// Workspace (~84 MB):
//   synb  bf16 [T,B,H]  @ 0          (26214400 B)  x_proj (read-only after GEMM)
//   state fp32 4x[B*H]  @ 52428800   (1048576 B)   volt, asc0, asc1, firing
//   F     bf16 [T,B,H]  @ 53477376   (26214400 B)  firing history
//     xb  bf16 [12800,512] overlays F (dead before first F write)
//   WinT  bf16 [H,IN]   @ 79691776   (1048576 B)
//   WlatT bf16 [H,H]    @ 80740352   (2097152 B)
//   WoutB bf16 [OUT,H]  @ 82837504   (1048576 B)

typedef float f32x4 __attribute__((ext_vector_type(4)));
typedef __bf16 bf16x8 __attribute__((ext_vector_type(8)));
typedef unsigned short ushortx8 __attribute__((ext_vector_type(8)));
typedef unsigned short ushortx4 __attribute__((ext_vector_type(4)));

__device__ __forceinline__ unsigned short f2b(float f) {
    unsigned int u = __float_as_uint(f);
    unsigned int r = u + 0x7FFFu + ((u >> 16) & 1u);   // RNE
    return (unsigned short)(r >> 16);
}
__device__ __forceinline__ float b2f(unsigned short u) {
    return __uint_as_float(((unsigned int)u) << 16);
}
__device__ __forceinline__ float sigmoidf(float x) {
    return 1.0f / (1.0f + __expf(-x));
}

// async global->LDS, 16 B per lane; lptr must be wave-uniform (HW adds lane*16)
__device__ __forceinline__ void gl_lds16(const unsigned short* g, unsigned short* l) {
    __builtin_amdgcn_global_load_lds(
        (const __attribute__((address_space(1))) void*)g,
        (__attribute__((address_space(3))) void*)l, 16, 0, 0);
}

// ---------------------------------------------------------------------------
// prep_all: one dispatch for all weight/input preprocessing (role by blockIdx).
// ---------------------------------------------------------------------------
__global__ __launch_bounds__(256) void prep_all(
    const float* __restrict__ W_in, const float* __restrict__ W_lat,
    const float* __restrict__ W_out, const float* __restrict__ x,
    unsigned short* __restrict__ WinT, unsigned short* __restrict__ WlatT,
    unsigned short* __restrict__ WoutB, unsigned short* __restrict__ xb)
{
    __shared__ unsigned short t[64][65];
    const int blk = blockIdx.x, tid = threadIdx.x;

    if (blk < 128) {                       // Win transpose
        int bx = (blk & 15) * 64, by = (blk >> 4) * 64;
        int tx = tid & 63, ty = tid >> 6;
        for (int r = ty; r < 64; r += 4)
            t[r][tx] = f2b(W_in[(size_t)(by + r) * 1024 + bx + tx]);
        __syncthreads();
        for (int r = ty; r < 64; r += 4)
            WinT[(size_t)(bx + r) * 512 + by + tx] = t[tx][r];
    } else if (blk < 384) {                // Wlat transpose
        int b2 = blk - 128;
        int bx = (b2 & 15) * 64, by = (b2 >> 4) * 64;
        int tx = tid & 63, ty = tid >> 6;
        for (int r = ty; r < 64; r += 4)
            t[r][tx] = f2b(W_lat[(size_t)(by + r) * 1024 + bx + tx]);
        __syncthreads();
        for (int r = ty; r < 64; r += 4)
            WlatT[(size_t)(bx + r) * 1024 + by + tx] = t[tx][r];
    } else if (blk < 896) {                // Wout convert
        int i = ((blk - 384) * 256 + tid) * 4;
        f32x4 v = *(const f32x4*)(W_out + i);
        ushortx4 o;
        o[0] = f2b(v[0]); o[1] = f2b(v[1]); o[2] = f2b(v[2]); o[3] = f2b(v[3]);
        *(ushortx4*)(WoutB + i) = o;
    } else {                               // x convert
        size_t i8 = (size_t)((blk - 896) * 256 + tid) * 8;
        int m = (int)(i8 >> 9), k = (int)(i8 & 511);
        int b = m & 63, tt = m >> 6;
        const float* src = x + ((size_t)b * 200 + tt) * 512 + k;
        f32x4 v0 = *(const f32x4*)src;
        f32x4 v1 = *(const f32x4*)(src + 4);
        ushortx8 o;
        o[0] = f2b(v0[0]); o[1] = f2b(v0[1]); o[2] = f2b(v0[2]); o[3] = f2b(v0[3]);
        o[4] = f2b(v1[0]); o[5] = f2b(v1[1]); o[6] = f2b(v1[2]); o[7] = f2b(v1[3]);
        *(ushortx8*)(xb + i8) = o;
    }
}

// ---------------------------------------------------------------------------
// NT GEMM: C[m,n] = sum_k A[m,k] * Bt[n,k]; A,Bt bf16 row-major K-contig.
// XCD-grouped swizzle: logical l = (d%8)*(nwg/8)+d/8 puts the N-tiles of each
// M-panel on ONE XCD (requires nwg % 8 == 0 — all launches satisfy this).
// MODE 0: zero init, BF16 out identity rows (outb).    (input projection)
// MODE 2: zero init, +bias, fp32 out remapped [B,T,OUT] (readout);
//         t_base = global t of local row 0 (rows are t-major: r -> t=r>>6).
// Block = 256 threads, 4 waves 2x2; wave tile (BM/2)x(BN/2); MFMA 16x16x32.
// ---------------------------------------------------------------------------
template<int BM, int BN, int MODE>
__global__ __launch_bounds__(256) void gemm_nt(
    const unsigned short* __restrict__ A,
    const unsigned short* __restrict__ Bt,
    float* __restrict__ outf,
    unsigned short* __restrict__ outb,
    const float* __restrict__ bias,
    int M, int N, int K, int t_base)
{
    constexpr int WM = BM / 2, WN = BN / 2;
    constexpr int TM = WM / 16, TN = WN / 16;

    __shared__ unsigned short Asm[BM * 64];
    __shared__ unsigned short Bsm[BN * 64];

    const int tid  = threadIdx.x;
    const int wave = tid >> 6, lane = tid & 63;
    const int m16  = lane & 15, quad = lane >> 4;
    // XCD-grouped block swizzle (bijective when nwg % 8 == 0)
    const int nwg = gridDim.x * gridDim.y;
    const int d   = blockIdx.y * gridDim.x + blockIdx.x;
    const int l   = (d & 7) * (nwg >> 3) + (d >> 3);
    const int bm0 = (l / gridDim.x) * BM, bn0 = (l % gridDim.x) * BN;
    const int wr   = (wave >> 1) * WM, wc = (wave & 1) * WN;
    const int sr   = lane >> 3;        // row within an 8-row staging group
    const int sc   = lane & 7;         // LDS 16B slot within the row

    f32x4 acc[TM][TN];
#pragma unroll
    for (int i = 0; i < TM; i++)
#pragma unroll
        for (int j = 0; j < TN; j++)
            acc[i][j] = (f32x4){0.f, 0.f, 0.f, 0.f};

    for (int k0 = 0; k0 < K; k0 += 64) {
        // async staging: each wave-instr fills 8 rows (1024 B) of LDS
#pragma unroll
        for (int g = wave; g < BM / 8; g += 4) {
            int r = g * 8 + sr;
            int c = sc ^ (r & 7);                       // global-side swizzle
            gl_lds16(A + (size_t)(bm0 + r) * K + k0 + c * 8, Asm + g * 512);
        }
#pragma unroll
        for (int g = wave; g < BN / 8; g += 4) {
            int r = g * 8 + sr;
            int c = sc ^ (r & 7);
            gl_lds16(Bt + (size_t)(bn0 + r) * K + k0 + c * 8, Bsm + g * 512);
        }
        __syncthreads();

        ushortx8 af[2][TM], bfr[2][TN];
#pragma unroll
        for (int kh = 0; kh < 2; kh++) {
#pragma unroll
            for (int i = 0; i < TM; i++) {
                int ra = wr + i * 16 + m16;
                af[kh][i] = *(const ushortx8*)(
                    Asm + ra * 64 + (((kh * 4 + quad) ^ (ra & 7)) * 8));
            }
#pragma unroll
            for (int j = 0; j < TN; j++) {
                int rb = wc + j * 16 + m16;
                bfr[kh][j] = *(const ushortx8*)(
                    Bsm + rb * 64 + (((kh * 4 + quad) ^ (rb & 7)) * 8));
            }
        }
#pragma unroll
        for (int i = 0; i < TM; i++)
#pragma unroll
            for (int j = 0; j < TN; j++) {
                acc[i][j] = __builtin_amdgcn_mfma_f32_16x16x32_bf16(
                    __builtin_bit_cast(bf16x8, af[0][i]),
                    __builtin_bit_cast(bf16x8, bfr[0][j]),
                    acc[i][j], 0, 0, 0);
                acc[i][j] = __builtin_amdgcn_mfma_f32_16x16x32_bf16(
                    __builtin_bit_cast(bf16x8, af[1][i]),
                    __builtin_bit_cast(bf16x8, bfr[1][j]),
                    acc[i][j], 0, 0, 0);
            }
        __syncthreads();
    }

    // epilogue; C/D layout: col = lane&15, row = quad*4 + reg  (m89-verified)
#pragma unroll
    for (int i = 0; i < TM; i++)
#pragma unroll
        for (int j = 0; j < TN; j++) {
            int col = bn0 + wc + j * 16 + m16;
            float bv = (MODE == 2) ? bias[col] : 0.f;
#pragma unroll
            for (int v = 0; v < 4; v++) {
                int row = bm0 + wr + i * 16 + quad * 4 + v;
                if (MODE == 2) {
                    size_t o = (size_t)((row & 63) * 200 + t_base + (row >> 6)) * N + col;
                    outf[o] = acc[i][j][v] + bv;
                } else {
                    outb[(size_t)row * N + col] = f2b(acc[i][j][v]);
                }
            }
        }
}

// ---------------------------------------------------------------------------
// Fused lateral GEMM + 20-step GLIFR recurrence for one chunk.
// first=1 (chunk 0): skip GEMM; recurrence straight from x_proj (bf16), zero
// initial state. first=0 (chunks 1..9): double-buffered K-loop (4 x K=256
// sub-steps, named buffers, STAGE(next) before COMPUTE(cur)) with acc init
// from bf16 x_proj. Block tile M = 80 rows (20t x 4b), N = 64 h; grid 256 =
// 1 block/CU. XCD-grouped swizzle: XCD k owns b-groups 2k,2k+1.
// LDS row = 512 B = 32 slots of 16 B; slot c of row r holds chunk c^(r&31).
// Waves 0,1 rows 0..47 (TM=3); waves 2,3 rows 48..79 (TM=2); TN=2.
// ---------------------------------------------------------------------------
__global__ __launch_bounds__(256) void fused_chunk(
    const unsigned short* __restrict__ Fprev, // [1280,1024] bf16, rows t*64+b
    const unsigned short* __restrict__ Wlat,  // [1024,1024] bf16 NT
    const unsigned short* __restrict__ xproj, // [1280,1024] bf16 (syn chunk c)
    float* __restrict__ state,                // 4 x [B*H]
    unsigned short* __restrict__ Fc,          // F chunk c out
    const float* __restrict__ thresh,
    const float* __restrict__ t_km,
    const float* __restrict__ t_ak,
    const float* __restrict__ amp,
    const float* __restrict__ t_ar,
    int first)
{
    const int BH = 64 * 1024;
    __shared__ __align__(16) char lds[147456];
    unsigned short* A0 = (unsigned short*)lds;             // 80*512 B = 40960
    unsigned short* A1 = (unsigned short*)(lds + 40960);   // 80*512 B
    unsigned short* B0 = (unsigned short*)(lds + 81920);   // 64*512 B = 32768
    unsigned short* B1 = (unsigned short*)(lds + 114688);  // 64*512 B
    float* synT = (float*)lds;                             // 80*66 f32 = 21120 B

    const int tid  = threadIdx.x;
    const int wave = tid >> 6, lane = tid & 63;
    const int m16  = lane & 15, quad = lane >> 4;
    const int sr2  = lane >> 5;        // row within a 2-row staging group
    const int sc32 = lane & 31;        // LDS 16B slot within the 512B row
    // XCD-grouped swizzle: XCD d%8 gets b-groups 2(d%8), 2(d%8)+1.
    const int d    = blockIdx.y * 16 + blockIdx.x;
    const int l    = (d & 7) * 32 + (d >> 3);
    const int b0   = (l >> 4) * 4, h0 = (l & 15) * 64;
    const int wrow = (wave >> 1) * 48;
    const int wc   = (wave & 1) * 32;

    // recurrence constants
    const int h    = h0 + lane;
    const int gidx = (b0 + wave) * 1024 + h;
    float th  = thresh[h];
    float sm  = sigmoidf(t_km[h]);             // DT*k_m
    float rm  = 0.1f * sm;                     // R_MEM*DT*k_m
    float om  = 1.0f - sm;
    float sa0 = sigmoidf(t_ak[h]);
    float sa1 = sigmoidf(t_ak[1024 + h]);
    float am0 = amp[h];
    float am1 = amp[1024 + h];
    float r0  = 1.0f - 2.0f * sigmoidf(t_ar[h]);
    float r1  = 1.0f - 2.0f * sigmoidf(t_ar[1024 + h]);

    if (first) {
        // ---- chunk 0: recurrence straight from x_proj, zero state ----
        float volt = 0.f, as0 = 0.f, as1 = 0.f, fir = 0.f;
#pragma unroll
        for (int s = 0; s < 20; s++) {
            float sv  = b2f(xproj[(size_t)(s * 64 + b0 + wave) * 1024 + h]);
            float na0 = (am0 + r0 * as0) * fir * sa0 + (1.f - sa0) * as0;
            float na1 = (am1 + r1 * as1) * fir * sa1 + (1.f - sa1) * as1;
            volt = rm * (sv + na0 + na1) + om * volt;
            fir  = sigmoidf(volt - th);
            Fc[(size_t)s * BH + gidx] = f2b(fir);
            as0 = na0; as1 = na1;
        }
        state[gidx]          = volt;
        state[BH + gidx]     = as0;
        state[2 * BH + gidx] = as1;
        state[3 * BH + gidx] = fir;
        return;
    }

    f32x4 acc[3][2];
    // acc init = x_proj tile (bf16)
#pragma unroll
    for (int i = 0; i < 3; i++) {
        if (i < 2 || wave < 2) {
#pragma unroll
            for (int j = 0; j < 2; j++)
#pragma unroll
                for (int v = 0; v < 4; v++) {
                    int row = wrow + i * 16 + quad * 4 + v;
                    int col = h0 + wc + j * 16 + m16;
                    acc[i][j][v] = b2f(
                        xproj[(size_t)(((row >> 2) << 6) + b0 + (row & 3)) * 1024 + col]);
                }
        }
    }

    // stage one K=256 sub-tile into (Ad, Bd); 18 gl_lds16 per wave
    auto STAGE = [&](unsigned short* Ad, unsigned short* Bd, int k0) {
        for (int g = wave; g < 40; g += 4) {
            int r = g * 2 + sr2;
            int c = sc32 ^ (r & 31);                    // global-side swizzle
            int m = ((r >> 2) << 6) + b0 + (r & 3);
            gl_lds16(Fprev + (size_t)m * 1024 + k0 + c * 8, Ad + g * 512);
        }
        for (int g = wave; g < 32; g += 4) {
            int r = g * 2 + sr2;
            int c = sc32 ^ (r & 31);
            gl_lds16(Wlat + (size_t)(h0 + r) * 1024 + k0 + c * 8, Bd + g * 512);
        }
    };
    // consume one K=256 sub-tile (two half-steps of the proven BK=128 pattern)
    auto COMPUTE = [&](const unsigned short* As, const unsigned short* Bs) {
#pragma unroll
        for (int half = 0; half < 2; half++) {
            ushortx8 af[4][3], bfr[4][2];
#pragma unroll
            for (int kh = 0; kh < 4; kh++) {
                int s = half * 16 + kh * 4 + quad;     // k-chunk index 0..31
#pragma unroll
                for (int i = 0; i < 3; i++) {
                    if (i < 2 || wave < 2) {
                        int ra = wrow + i * 16 + m16;
                        af[kh][i] = *(const ushortx8*)(
                            As + ra * 256 + ((s ^ (ra & 31)) * 8));
                    }
                }
#pragma unroll
                for (int j = 0; j < 2; j++) {
                    int rb = wc + j * 16 + m16;
                    bfr[kh][j] = *(const ushortx8*)(
                        Bs + rb * 256 + ((s ^ (rb & 31)) * 8));
                }
            }
#pragma unroll
            for (int i = 0; i < 3; i++) {
                if (i < 2 || wave < 2) {
#pragma unroll
                    for (int j = 0; j < 2; j++) {
#pragma unroll
                        for (int kh = 0; kh < 4; kh++) {
                            acc[i][j] = __builtin_amdgcn_mfma_f32_16x16x32_bf16(
                                __builtin_bit_cast(bf16x8, af[kh][i]),
                                __builtin_bit_cast(bf16x8, bfr[kh][j]), acc[i][j], 0, 0, 0);
                        }
                    }
                }
            }
        }
    };

    // 2-phase pipeline, fully unrolled (static buffer pointers):
    STAGE(A0, B0, 0);
    __syncthreads();                        // fill drain (only full drain)
    STAGE(A1, B1, 256);  COMPUTE(A0, B0);  __syncthreads();
    STAGE(A0, B0, 512);  COMPUTE(A1, B1);  __syncthreads();
    STAGE(A1, B1, 768);  COMPUTE(A0, B0);  __syncthreads();
                         COMPUTE(A1, B1);  __syncthreads();

    // spill syn tile to LDS (overlays buffer 0; safe after final barrier).
#pragma unroll
    for (int i = 0; i < 3; i++) {
        if (i < 2 || wave < 2) {
#pragma unroll
            for (int j = 0; j < 2; j++)
#pragma unroll
                for (int v = 0; v < 4; v++) {
                    int row = wrow + i * 16 + quad * 4 + v;
                    synT[row * 66 + wc + j * 16 + m16] = acc[i][j][v];
                }
        }
    }
    __syncthreads();

    // 20-step recurrence: thread -> (b = wave, h = lane)
    float volt = state[gidx];
    float as0  = state[BH + gidx];
    float as1  = state[2 * BH + gidx];
    float fir  = state[3 * BH + gidx];

#pragma unroll
    for (int s = 0; s < 20; s++) {
        float sv  = synT[(s * 4 + wave) * 66 + lane];
        float na0 = (am0 + r0 * as0) * fir * sa0 + (1.f - sa0) * as0;
        float na1 = (am1 + r1 * as1) * fir * sa1 + (1.f - sa1) * as1;
        volt = rm * (sv + na0 + na1) + om * volt;
        fir  = sigmoidf(volt - th);
        Fc[(size_t)s * BH + gidx] = f2b(fir);
        as0 = na0; as1 = na1;
    }
    state[gidx]          = volt;
    state[BH + gidx]     = as0;
    state[2 * BH + gidx] = as1;
    state[3 * BH + gidx] = fir;
}

// ---------------------------------------------------------------------------
extern "C" void kernel_launch(void* const* d_in, const int* in_sizes, int n_in,
                              void* d_out, int out_size, void* d_ws, size_t ws_size,
                              hipStream_t stream)
{
    const float* x      = (const float*)d_in[0];  // [64,200,512]
    const float* W_in   = (const float*)d_in[1];  // [512,1024]
    const float* W_lat  = (const float*)d_in[2];  // [1024,1024]
    const float* thresh = (const float*)d_in[3];  // [1,1024]
    const float* t_km   = (const float*)d_in[4];  // [1,1024]
    const float* t_ak   = (const float*)d_in[5];  // [2,1,1024]
    const float* amp    = (const float*)d_in[6];  // [2,1,1024]
    const float* t_ar   = (const float*)d_in[7];  // [2,1,1024]
    const float* W_out  = (const float*)d_in[8];  // [512,1024] (n,k) already!
    const float* b_out  = (const float*)d_in[9];  // [512]
    float* out = (float*)d_out;                   // [64,200,512]

    char* ws = (char*)d_ws;
    unsigned short* synb  = (unsigned short*)ws;            // [T,B,H] bf16 x_proj
    float*          state = (float*)(ws + 52428800);
    unsigned short* F     = (unsigned short*)(ws + 53477376);
    unsigned short* xb    = F;  // overlay: dead before first F write
    unsigned short* WinT  = (unsigned short*)(ws + 79691776);
    unsigned short* WlatT = (unsigned short*)(ws + 80740352);
    unsigned short* WoutB = (unsigned short*)(ws + 82837504);

    // Prep (one dispatch): transposes/converts to bf16 NT layout, x to m-order.
    prep_all<<<4096, 256, 0, stream>>>(W_in, W_lat, W_out, x,
                                       WinT, WlatT, WoutB, xb);

    // x_proj (= synb bf16, read-only from here on): [12800,1024] = xb @ WinT^T
    gemm_nt<128, 128, 0><<<dim3(1024 / 128, 12800 / 128), 256, 0, stream>>>(
        xb, WinT, nullptr, synb, nullptr, 12800, 1024, 512, 0);

    const size_t CHUNK = 20 * 64 * 1024;  // elements per chunk of [T,B,H]
    // chunk 0 (first=1: no lateral term, zero state) then chunks 1..9
    fused_chunk<<<dim3(16, 16), 256, 0, stream>>>(
        F, WlatT, synb, state, F, thresh, t_km, t_ak, amp, t_ar, 1);
    for (int c = 1; c < 10; c++) {
        fused_chunk<<<dim3(16, 16), 256, 0, stream>>>(
            F + (size_t)(c - 1) * CHUNK, WlatT,
            synb + (size_t)c * CHUNK, state, F + (size_t)c * CHUNK,
            thresh, t_km, t_ak, amp, t_ar, 0);
    }

    // readout: out[b,t,:] = F[t,b,:] @ W_out^T + b_out  (W_out already [n,k])
    gemm_nt<128, 128, 2><<<dim3(512 / 128, 12800 / 128), 256, 0, stream>>>(
        F, WoutB, out, nullptr, b_out, 12800, 512, 1024, 0);
}